// Round 15
// baseline (201.537 us; speedup 1.0000x reference)
//
#include <hip/hip_runtime.h>

typedef float fx4 __attribute__((ext_vector_type(4)));
typedef short s16x8 __attribute__((ext_vector_type(8)));
typedef short s16x4 __attribute__((ext_vector_type(4)));
typedef unsigned short ushort_t;

__device__ __forceinline__ short f2bf(float f) {
  union { float f; unsigned u; } v; v.f = f;
  unsigned r = v.u + 0x7FFFu + ((v.u >> 16) & 1u);   // RNE to bf16
  return (short)(r >> 16);
}

__device__ __forceinline__ float bf2f(short h) {
  union { float f; unsigned u; } v;
  v.u = ((unsigned)(unsigned short)h) << 16;
  return v.f;
}

__device__ __forceinline__ unsigned cvt_pk_bf16(float a, float b) {
  unsigned r;
  asm("v_cvt_pk_bf16_f32 %0, %1, %2" : "=v"(r) : "v"(a), "v"(b));
  return r;
}

__device__ __forceinline__ s16x8 cvt8(fx4 a, fx4 b) {
  union { s16x8 s; unsigned u[4]; } w;
  w.u[0] = cvt_pk_bf16(a[0], a[1]);
  w.u[1] = cvt_pk_bf16(a[2], a[3]);
  w.u[2] = cvt_pk_bf16(b[0], b[1]);
  w.u[3] = cvt_pk_bf16(b[2], b[3]);
  return w.s;
}

__device__ __forceinline__ void gload16(const void* g, void* l) {
  __builtin_amdgcn_global_load_lds(
      (const __attribute__((address_space(1))) unsigned int*)g,
      (__attribute__((address_space(3))) unsigned int*)l, 16, 0, 0);
}

// ---------------------------------------------------------------------------
// prep: all 5 weight transposes W[K][N] fp32 -> Wt[N][K] bf16.
// ---------------------------------------------------------------------------
__global__ __launch_bounds__(256) void prep_kernel(
    const float* __restrict__ W1, const float* __restrict__ in_w,
    const float* __restrict__ out_w, const float* __restrict__ ff1_w,
    const float* __restrict__ ff2_w,
    ushort_t* __restrict__ W1t, ushort_t* __restrict__ in_wT,
    ushort_t* __restrict__ out_wT, ushort_t* __restrict__ ff1t,
    ushort_t* __restrict__ ff2t) {
  const int bid = blockIdx.x, t = threadIdx.x;
  const float* W; ushort_t* Wt; int K, N, base;
  if (bid < 256)       { W = W1;    Wt = W1t;    K = 256; N = 256; base = 0; }
  else if (bid < 1024) { W = in_w;  Wt = in_wT;  K = 256; N = 768; base = 256; }
  else if (bid < 1280) { W = out_w; Wt = out_wT; K = 256; N = 256; base = 1024; }
  else if (bid < 1792) { W = ff1_w; Wt = ff1t;   K = 256; N = 512; base = 1280; }
  else                 { W = ff2_w; Wt = ff2t;   K = 512; N = 256; base = 1792; }
  const int idx = (bid - base) * 256 + t;
  const int k = idx / N, n = idx - k * N;
  Wt[(size_t)n * K + k] = (ushort_t)f2bf(W[idx]);
}

// ---------------------------------------------------------------------------
// Unified 2-phase MFMA GEMM (round-6 structure, verified) — small GEMMs.
// ---------------------------------------------------------------------------
template<int MF, bool AF32, int OUTM, bool RELU, bool RES>
__global__ __launch_bounds__(256) void gemm2(
    const void* __restrict__ Av, const ushort_t* __restrict__ Bt,
    const float* __restrict__ bias, const float* __restrict__ res,
    const float* __restrict__ lns, const float* __restrict__ lnb,
    float* __restrict__ Cf, ushort_t* __restrict__ Cb,
    int M, int N, int K, int kLen) {
  constexpr int BM = MF * 16;
  __shared__ __align__(16) ushort_t Asm[2][BM * 64];
  __shared__ __align__(16) ushort_t Bsm[256 * 64];
  const int t = threadIdx.x, lane = t & 63, wave = t >> 6;
  const int bm = blockIdx.y * BM;
  const int bn = blockIdx.x * 256;
  const int wn = wave * 64, fr = lane & 15, fq = lane >> 4;
  const int NT = kLen >> 6;
  const int x0 = ((fq) ^ (fr & 7)) * 8;
  const int x1 = ((4 + fq) ^ (fr & 7)) * 8;
  fx4 acc[MF][4] = {};

  const int gl = lane >> 3, gc = lane & 7;
  const int gsw = (gc ^ gl) * 8;
  const ushort_t* Bgl = Bt + (size_t)(bn + wave * 64 + gl) * K + gsw;
  const ushort_t* Agl =
      (const ushort_t*)Av + (size_t)(bm + wave * (BM / 4) + gl) * K + gsw;
  constexpr int TPR = 256 / BM;
  const int arow = t / TPR;
  const int ac0 = (t % TPR) * (BM / 4);
  const float* Afp = (const float*)Av + (size_t)(bm + arow) * K + ac0;
  fx4 R[MF / 2][2];

  auto issueB = [&](int kt) {
    #pragma unroll
    for (int i = 0; i < 8; ++i)
      gload16(Bgl + (size_t)i * 8 * K + kt * 64, &Bsm[wave * 4096 + i * 512]);
  };
  auto issueAg = [&](int buf, int kt) {
    #pragma unroll
    for (int i = 0; i < MF / 2; ++i)
      gload16(Agl + (size_t)i * 8 * K + kt * 64,
              &Asm[buf][wave * (BM * 16) + i * 512]);
  };
  auto loadR = [&](int kt) {
    #pragma unroll
    for (int w = 0; w < MF / 2; ++w) {
      R[w][0] = *(const fx4*)(Afp + kt * 64 + w * 8);
      R[w][1] = *(const fx4*)(Afp + kt * 64 + w * 8 + 4);
    }
  };
  auto writeA = [&](int buf) {
    #pragma unroll
    for (int w = 0; w < MF / 2; ++w) {
      const int cs = ((ac0 >> 3) + w) ^ (arow & 7);
      *(s16x8*)&Asm[buf][arow * 64 + cs * 8] = cvt8(R[w][0], R[w][1]);
    }
  };

  if constexpr (AF32) { loadR(0); issueB(0); writeA(0); loadR(1); }
  else { issueAg(0, 0); issueB(0); }
  __syncthreads();

  #pragma unroll 1
  for (int kt = 0; kt < NT; ++kt) {
    const int cur = kt & 1;
    s16x8 b0[4], b1[4], a0[MF], a1[MF];
    #pragma unroll
    for (int nf = 0; nf < 4; ++nf) {
      b0[nf] = *(const s16x8*)&Bsm[(wn + nf * 16 + fr) * 64 + x0];
      b1[nf] = *(const s16x8*)&Bsm[(wn + nf * 16 + fr) * 64 + x1];
    }
    #pragma unroll
    for (int mf = 0; mf < MF; ++mf)
      a0[mf] = *(const s16x8*)&Asm[cur][(mf * 16 + fr) * 64 + x0];
    asm volatile("s_waitcnt lgkmcnt(0)" ::: "memory");
    if (kt + 1 < NT) {
      if constexpr (AF32) {
        writeA(cur ^ 1);
        if (kt + 2 < NT) loadR(kt + 2);
        issueB(kt + 1);
      } else {
        issueAg(cur ^ 1, kt + 1);
        issueB(kt + 1);
      }
    }
    #pragma unroll
    for (int mf = 0; mf < MF; ++mf)
      #pragma unroll
      for (int nf = 0; nf < 4; ++nf)
        acc[mf][nf] = __builtin_amdgcn_mfma_f32_16x16x32_bf16(
            a0[mf], b0[nf], acc[mf][nf], 0, 0, 0);
    #pragma unroll
    for (int mf = 0; mf < MF; ++mf)
      a1[mf] = *(const s16x8*)&Asm[cur][(mf * 16 + fr) * 64 + x1];
    #pragma unroll
    for (int mf = 0; mf < MF; ++mf)
      #pragma unroll
      for (int nf = 0; nf < 4; ++nf)
        acc[mf][nf] = __builtin_amdgcn_mfma_f32_16x16x32_bf16(
            a1[mf], b1[nf], acc[mf][nf], 0, 0, 0);
    __syncthreads();
  }

  if constexpr (OUTM == 3) {
    #pragma unroll
    for (int mf = 0; mf < MF; ++mf)
      #pragma unroll
      for (int nf = 0; nf < 4; ++nf) {
        const int col = bn + wn + nf * 16 + fr;
        const float bb = bias[col];
        s16x4 w;
        #pragma unroll
        for (int r = 0; r < 4; ++r) w[r] = f2bf(acc[mf][nf][r] + bb);
        *(s16x4*)&Cb[(size_t)col * M + bm + mf * 16 + fq * 4] = w;
      }
  } else {
    #pragma unroll
    for (int mf = 0; mf < MF; ++mf)
      #pragma unroll
      for (int nf = 0; nf < 4; ++nf) {
        const int col = bn + wn + nf * 16 + fr;
        const float bb = bias[col];
        #pragma unroll
        for (int r = 0; r < 4; ++r) {
          const int row = bm + mf * 16 + fq * 4 + r;
          float x = acc[mf][nf][r] + bb;
          if constexpr (RES) x += res[(size_t)row * N + col];
          if constexpr (RELU) x = fmaxf(x, 0.f);
          if constexpr (OUTM == 0 || OUTM == 2) Cf[(size_t)row * N + col] = x;
          if constexpr (OUTM == 1 || OUTM == 2)
            Cb[(size_t)row * N + col] = (ushort_t)f2bf(x);
        }
      }
  }
}

// ---------------------------------------------------------------------------
// adjmm7: part[kh] = adj[:, kh*2048:+2048] @ x-chunk, bf16 partials.
// BM=128 x BN=128: B re-read traffic (M/BM)* (BN-share) = 256 MB total
// (halved vs BM=64/BN=256) at only 64 acc-VGPRs/thread (8mf x 2nf).
// 4 waves, wave w owns cols [w*32, +32) -> wave-private 32-row B slab
// (4 gloads). A: 2 threads/row fp32->reg->cvt_pk->swizzled ds_write (r14
// layout, verified). dbuf A (32K) + dbuf B (32K) = 64 KB -> 2 blocks/CU.
// r9's counted-vmcnt schedule: end-of-iter vmcnt(8) drains only B(kt+1);
// loadR(kt+2) stays in flight across the barrier.
// ---------------------------------------------------------------------------
__global__ __launch_bounds__(256) void adjmm7(
    const float* __restrict__ adj, const ushort_t* __restrict__ xT,
    ushort_t* __restrict__ part) {
  constexpr int NT = 32;                      // 2048 / 64
  __shared__ __align__(16) ushort_t Asm[2][128 * 64];  // 32 KB
  __shared__ __align__(16) ushort_t Bsm[2][128 * 64];  // 32 KB
  const int t = threadIdx.x, lane = t & 63, wave = t >> 6;
  const int kh = blockIdx.x, bm = blockIdx.y * 128, bn = blockIdx.z * 128;
  const int kOff = kh * 2048;
  const int wn = wave * 32, fr = lane & 15, fq = lane >> 4;
  const int x0 = (fq ^ (fr & 7)) * 8, x1 = ((4 + fq) ^ (fr & 7)) * 8;
  const int gl = lane >> 3, gsw = ((lane & 7) ^ gl) * 8;

  const ushort_t* Bgl = xT + (size_t)(bn + wn + gl) * 8192 + kOff + gsw;
  const int arow = t >> 1;                    // 2 threads/row, 128 rows
  const int alane = t & 1;
  const float* Afp = adj + (size_t)(bm + arow) * 8192 + kOff;

  fx4 R[8];                   // load j covers floats [alane*4 + j*8, +4)
  auto loadR = [&](int kt) {
    #pragma unroll
    for (int j = 0; j < 8; ++j)
      R[j] = *(const fx4*)(Afp + kt * 64 + alane * 4 + j * 8);
  };
  auto writeA = [&](int buf) {
    #pragma unroll
    for (int j = 0; j < 8; ++j) {
      union { s16x4 s; unsigned u[2]; } w;
      w.u[0] = cvt_pk_bf16(R[j][0], R[j][1]);
      w.u[1] = cvt_pk_bf16(R[j][2], R[j][3]);
      *(s16x4*)&Asm[buf][arow * 64 + (j ^ (arow & 7)) * 8 + alane * 4] = w.s;
    }
  };
  auto issueB = [&](int buf, int kt) {
    #pragma unroll
    for (int i = 0; i < 4; ++i)
      gload16(Bgl + (size_t)i * 8 * 8192 + kt * 64,
              &Bsm[buf][wave * 2048 + i * 512]);
  };

  fx4 acc[8][2] = {};
  // prologue: A0 staged; A1 in R... -> A(1) flying; B(0) landing, B(1) flying
  loadR(0);                                   // 8 loads
  issueB(0, 0);                               // 4 loads
  writeA(0);                                  // waits loadR(0) (auto vmcnt)
  loadR(1);                                   // 8 loads
  asm volatile("s_waitcnt lgkmcnt(0)" ::: "memory");
  asm volatile("s_waitcnt vmcnt(8)" ::: "memory");   // B(0) landed; loadR(1) flies
  __builtin_amdgcn_sched_barrier(0);
  __builtin_amdgcn_s_barrier();
  __builtin_amdgcn_sched_barrier(0);
  issueB(1, 1);

  #pragma unroll 1
  for (int kt = 0; kt < NT; ++kt) {
    const int cur = kt & 1;
    s16x8 a0[8], b0[2], b1[2];
    #pragma unroll
    for (int nf = 0; nf < 2; ++nf) {
      b0[nf] = *(const s16x8*)&Bsm[cur][(wn + nf * 16 + fr) * 64 + x0];
      b1[nf] = *(const s16x8*)&Bsm[cur][(wn + nf * 16 + fr) * 64 + x1];
    }
    #pragma unroll
    for (int mf = 0; mf < 8; ++mf)
      a0[mf] = *(const s16x8*)&Asm[cur][(mf * 16 + fr) * 64 + x0];
    if (kt + 1 < NT) {
      writeA(cur ^ 1);                        // waits loadR(kt+1) (auto vmcnt)
      if (kt + 2 < NT) loadR(kt + 2);         // 8 loads
    }
    #pragma unroll
    for (int mf = 0; mf < 8; ++mf)
      #pragma unroll
      for (int nf = 0; nf < 2; ++nf)
        acc[mf][nf] = __builtin_amdgcn_mfma_f32_16x16x32_bf16(
            a0[mf], b0[nf], acc[mf][nf], 0, 0, 0);
    #pragma unroll
    for (int mf = 0; mf < 8; ++mf)
      a0[mf] = *(const s16x8*)&Asm[cur][(mf * 16 + fr) * 64 + x1];
    #pragma unroll
    for (int mf = 0; mf < 8; ++mf)
      #pragma unroll
      for (int nf = 0; nf < 2; ++nf)
        acc[mf][nf] = __builtin_amdgcn_mfma_f32_16x16x32_bf16(
            a0[mf], b1[nf], acc[mf][nf], 0, 0, 0);
    asm volatile("s_waitcnt lgkmcnt(0)" ::: "memory");
    if (kt + 2 < NT)
      asm volatile("s_waitcnt vmcnt(8)" ::: "memory");   // B(kt+1) landed
    else
      asm volatile("s_waitcnt vmcnt(0)" ::: "memory");
    __builtin_amdgcn_sched_barrier(0);
    __builtin_amdgcn_s_barrier();
    __builtin_amdgcn_sched_barrier(0);
    if (kt + 2 < NT) issueB(cur, kt + 2);
  }

  ushort_t* po = part + (size_t)kh * (8192ull * 256ull);
  #pragma unroll
  for (int mf = 0; mf < 8; ++mf)
    #pragma unroll
    for (int nf = 0; nf < 2; ++nf)
      #pragma unroll
      for (int r = 0; r < 4; ++r)
        po[(size_t)(bm + mf * 16 + fq * 4 + r) * 256 + bn + wn + nf * 16 + fr] =
            (ushort_t)f2bf(acc[mf][nf][r]);
}

// sum 4 bf16 partials + relu -> p fp32 + p_bf bf16
__global__ __launch_bounds__(256) void relu_reduce4(
    const ushort_t* __restrict__ part, float* __restrict__ p,
    ushort_t* __restrict__ pb) {
  const size_t i = ((size_t)blockIdx.x * 256 + threadIdx.x) * 8;
  const size_t S = 8192ull * 256ull;
  float a[8] = {};
  #pragma unroll
  for (int j = 0; j < 4; ++j) {
    const s16x8 v = *(const s16x8*)(part + j * S + i);
    #pragma unroll
    for (int c = 0; c < 8; ++c) a[c] += bf2f(v[c]);
  }
  fx4 v0, v1;
  #pragma unroll
  for (int c = 0; c < 4; ++c) {
    v0[c] = fmaxf(a[c], 0.f);
    v1[c] = fmaxf(a[c + 4], 0.f);
  }
  *(fx4*)(p + i) = v0;
  *(fx4*)(p + i + 4) = v1;
  s16x8 w;
  #pragma unroll
  for (int c = 0; c < 4; ++c) { w[c] = f2bf(v0[c]); w[c + 4] = f2bf(v1[c]); }
  *(s16x8*)(pb + i) = w;
}

// ---------------------------------------------------------------------------
// Fused attention, bf16 qkv input. One block per (graph, head).
// ---------------------------------------------------------------------------
__global__ __launch_bounds__(256) void att_fused(
    const ushort_t* __restrict__ qkv, ushort_t* __restrict__ attout) {
  __shared__ float k_s[128][68];
  __shared__ float v_s[128][68];
  __shared__ float s_s[128][129];
  __shared__ float pm[2][128];
  __shared__ float ps[2][128];
  const int bh = blockIdx.x, b = bh >> 2, h = bh & 3;
  const int t = threadIdx.x;
  const ushort_t* qb = qkv + (size_t)b * 128 * 768 + h * 64;
  for (int u = t; u < 1024; u += 256) {
    const int n = u >> 3, d8 = (u & 7) * 8;
    const s16x8 kk = *(const s16x8*)(qb + (size_t)n * 768 + 256 + d8);
    const s16x8 vv = *(const s16x8*)(qb + (size_t)n * 768 + 512 + d8);
    #pragma unroll
    for (int c = 0; c < 8; ++c) {
      k_s[n][d8 + c] = bf2f(kk[c]);
      v_s[n][d8 + c] = bf2f(vv[c]);
    }
  }
  const int row = t & 127, kh = t >> 7;
  fx4 qr[16];
  {
    const s16x8* q8 = (const s16x8*)(qb + (size_t)row * 768);
    #pragma unroll
    for (int j = 0; j < 8; ++j) {
      const s16x8 qv = q8[j];
      qr[2*j][0] = bf2f(qv[0]); qr[2*j][1] = bf2f(qv[1]);
      qr[2*j][2] = bf2f(qv[2]); qr[2*j][3] = bf2f(qv[3]);
      qr[2*j+1][0] = bf2f(qv[4]); qr[2*j+1][1] = bf2f(qv[5]);
      qr[2*j+1][2] = bf2f(qv[6]); qr[2*j+1][3] = bf2f(qv[7]);
    }
  }
  __syncthreads();
  float m = -1e30f;
  for (int j = 0; j < 64; ++j) {
    const int jj = kh * 64 + j;
    const fx4* kr = (const fx4*)&k_s[jj][0];
    float s0 = 0.f, s1 = 0.f, s2 = 0.f, s3 = 0.f;
    #pragma unroll
    for (int c = 0; c < 16; c += 4) {
      fx4 k0 = kr[c], k1 = kr[c + 1], k2 = kr[c + 2], k3 = kr[c + 3];
      s0 += qr[c][0]*k0[0] + qr[c][1]*k0[1] + qr[c][2]*k0[2] + qr[c][3]*k0[3];
      s1 += qr[c+1][0]*k1[0] + qr[c+1][1]*k1[1] + qr[c+1][2]*k1[2] + qr[c+1][3]*k1[3];
      s2 += qr[c+2][0]*k2[0] + qr[c+2][1]*k2[1] + qr[c+2][2]*k2[2] + qr[c+2][3]*k2[3];
      s3 += qr[c+3][0]*k3[0] + qr[c+3][1]*k3[1] + qr[c+3][2]*k3[2] + qr[c+3][3]*k3[3];
    }
    const float s = (s0 + s1 + s2 + s3) * 0.125f;
    s_s[row][jj] = s;
    m = fmaxf(m, s);
  }
  pm[kh][row] = m;
  __syncthreads();
  const float m2 = fmaxf(pm[0][row], pm[1][row]);
  float sum = 0.f;
  for (int j = 0; j < 64; ++j) {
    const int jj = kh * 64 + j;
    const float e = __expf(s_s[row][jj] - m2);
    s_s[row][jj] = e;
    sum += e;
  }
  ps[kh][row] = sum;
  __syncthreads();
  const int row2 = t >> 1, dh = (t & 1) * 32;
  const float inv = 1.f / (ps[0][row2] + ps[1][row2]);
  fx4 acc4[8] = {};
  for (int k = 0; k < 128; ++k) {
    const float e = s_s[row2][k];
    const fx4* vr = (const fx4*)&v_s[k][dh];
    #pragma unroll
    for (int c = 0; c < 8; ++c) acc4[c] += e * vr[c];
  }
  ushort_t* orow = attout + (size_t)(b * 128 + row2) * 256 + h * 64 + dh;
  #pragma unroll
  for (int c = 0; c < 8; ++c) {
    const fx4 v = acc4[c] * inv;
    s16x4 w;
    #pragma unroll
    for (int j = 0; j < 4; ++j) w[j] = f2bf(v[j]);
    *(s16x4*)(orow + c * 4) = w;
  }
}

// ---------------------------------------------------------------------------
// Fused tail: outproj+res+LN1 -> ff1+relu -> ff2+res+LN2 -> 32-row col-sums.
// ---------------------------------------------------------------------------
__global__ __launch_bounds__(256) void tail_kernel(
    const ushort_t* __restrict__ attout, const ushort_t* __restrict__ out_wT,
    const float* __restrict__ out_b, const float* __restrict__ p_res,
    const float* __restrict__ ln1_s, const float* __restrict__ ln1_b,
    const ushort_t* __restrict__ ff1t, const float* __restrict__ ff1_b,
    const ushort_t* __restrict__ ff2t, const float* __restrict__ ff2_b,
    const float* __restrict__ ln2_s, const float* __restrict__ ln2_b,
    float* __restrict__ pooled4) {
  __shared__ __align__(16) ushort_t Asm[2][32 * 64];
  __shared__ __align__(16) ushort_t Bsm[256 * 64];
  __shared__ __align__(16) ushort_t y_s[32 * 256];
  __shared__ __align__(16) ushort_t f1_s[32 * 512];
  __shared__ float red_s[128], red_q[128];
  const int t = threadIdx.x, lane = t & 63, wave = t >> 6;
  const int bq = blockIdx.x, bm = bq * 32;
  const int wn = wave * 64, fr = lane & 15, fq = lane >> 4;
  const int x0 = (fq ^ (fr & 7)) * 8, x1 = ((4 + fq) ^ (fr & 7)) * 8;
  const int gl = lane >> 3, gc = lane & 7, gsw = (gc ^ gl) * 8;

  fx4 acc[2][4] = {};
  // ---------------- phase A: z = attout@out_w + b + p; y = LN1(z) ----------
  {
    const ushort_t* Agl = attout + (size_t)(bm + wave * 8 + gl) * 256 + gsw;
    const ushort_t* Bgl = out_wT + (size_t)(wave * 64 + gl) * 256 + gsw;
    auto issueA = [&](int buf, int kt) {
      gload16(Agl + kt * 64, &Asm[buf][wave * 512]);
    };
    auto issueB = [&](int kt) {
      #pragma unroll
      for (int i = 0; i < 8; ++i)
        gload16(Bgl + (size_t)i * 8 * 256 + kt * 64,
                &Bsm[wave * 4096 + i * 512]);
    };
    issueA(0, 0); issueB(0);
    __syncthreads();
    #pragma unroll 1
    for (int kt = 0; kt < 4; ++kt) {
      const int cur = kt & 1;
      s16x8 b0[4], b1[4], a0[2], a1[2];
      #pragma unroll
      for (int nf = 0; nf < 4; ++nf) {
        b0[nf] = *(const s16x8*)&Bsm[(wn + nf * 16 + fr) * 64 + x0];
        b1[nf] = *(const s16x8*)&Bsm[(wn + nf * 16 + fr) * 64 + x1];
      }
      #pragma unroll
      for (int mf = 0; mf < 2; ++mf) {
        a0[mf] = *(const s16x8*)&Asm[cur][(mf * 16 + fr) * 64 + x0];
        a1[mf] = *(const s16x8*)&Asm[cur][(mf * 16 + fr) * 64 + x1];
      }
      asm volatile("s_waitcnt lgkmcnt(0)" ::: "memory");
      if (kt < 3) { issueA(cur ^ 1, kt + 1); issueB(kt + 1); }
      #pragma unroll
      for (int mf = 0; mf < 2; ++mf)
        #pragma unroll
        for (int nf = 0; nf < 4; ++nf) {
          acc[mf][nf] = __builtin_amdgcn_mfma_f32_16x16x32_bf16(
              a0[mf], b0[nf], acc[mf][nf], 0, 0, 0);
          acc[mf][nf] = __builtin_amdgcn_mfma_f32_16x16x32_bf16(
              a1[mf], b1[nf], acc[mf][nf], 0, 0, 0);
        }
      __syncthreads();
    }
  }
  float yv[2][4][4];
  #pragma unroll
  for (int mf = 0; mf < 2; ++mf)
    #pragma unroll
    for (int nf = 0; nf < 4; ++nf) {
      const int col = wn + nf * 16 + fr;
      #pragma unroll
      for (int r = 0; r < 4; ++r) {
        const int row = bm + mf * 16 + fq * 4 + r;
        yv[mf][nf][r] = acc[mf][nf][r] + out_b[col] +
                        p_res[(size_t)row * 256 + col];
      }
    }
  {
    #pragma unroll
    for (int mf = 0; mf < 2; ++mf)
      #pragma unroll
      for (int r = 0; r < 4; ++r) {
        float s = yv[mf][0][r] + yv[mf][1][r] + yv[mf][2][r] + yv[mf][3][r];
        float q = yv[mf][0][r]*yv[mf][0][r] + yv[mf][1][r]*yv[mf][1][r] +
                  yv[mf][2][r]*yv[mf][2][r] + yv[mf][3][r]*yv[mf][3][r];
        #pragma unroll
        for (int off = 1; off < 16; off <<= 1) {
          s += __shfl_xor(s, off, 64);
          q += __shfl_xor(q, off, 64);
        }
        if (fr == 0) {
          red_s[(mf * 16 + fq * 4 + r) * 4 + wave] = s;
          red_q[(mf * 16 + fq * 4 + r) * 4 + wave] = q;
        }
      }
    __syncthreads();
    #pragma unroll
    for (int mf = 0; mf < 2; ++mf)
      #pragma unroll
      for (int r = 0; r < 4; ++r) {
        const int rl = mf * 16 + fq * 4 + r;
        const float st = red_s[rl*4] + red_s[rl*4+1] + red_s[rl*4+2] + red_s[rl*4+3];
        const float qt = red_q[rl*4] + red_q[rl*4+1] + red_q[rl*4+2] + red_q[rl*4+3];
        const float mu = st * (1.f / 256.f);
        const float rr = rsqrtf(qt * (1.f / 256.f) - mu * mu + 1e-5f);
        #pragma unroll
        for (int nf = 0; nf < 4; ++nf) {
          const int col = wn + nf * 16 + fr;
          const float o = (yv[mf][nf][r] - mu) * rr * ln1_s[col] + ln1_b[col];
          yv[mf][nf][r] = o;
          y_s[rl * 256 + ((col >> 3) ^ (rl & 7)) * 8 + (col & 7)] =
              (ushort_t)f2bf(o);
        }
      }
  }
  __syncthreads();

  // ---------------- phase B: f1 = relu(y @ ff1_w + b) ----------------------
  #pragma unroll 1
  for (int ng = 0; ng < 2; ++ng) {
    const ushort_t* Bgl = ff1t + (size_t)(ng * 256 + wave * 64 + gl) * 256 + gsw;
    auto issueB = [&](int kt) {
      #pragma unroll
      for (int i = 0; i < 8; ++i)
        gload16(Bgl + (size_t)i * 8 * 256 + kt * 64,
                &Bsm[wave * 4096 + i * 512]);
    };
    fx4 a2[2][4] = {};
    issueB(0);
    #pragma unroll 1
    for (int kt = 0; kt < 4; ++kt) {
      asm volatile("s_waitcnt vmcnt(0)" ::: "memory");
      s16x8 b0[4], b1[4], a0[2], a1[2];
      #pragma unroll
      for (int nf = 0; nf < 4; ++nf) {
        b0[nf] = *(const s16x8*)&Bsm[(wn + nf * 16 + fr) * 64 + x0];
        b1[nf] = *(const s16x8*)&Bsm[(wn + nf * 16 + fr) * 64 + x1];
      }
      #pragma unroll
      for (int mf = 0; mf < 2; ++mf) {
        const int row = mf * 16 + fr;
        a0[mf] = *(const s16x8*)&y_s[row * 256 + ((kt*8 + fq) ^ (row & 7)) * 8];
        a1[mf] = *(const s16x8*)&y_s[row * 256 + ((kt*8 + 4 + fq) ^ (row & 7)) * 8];
      }
      asm volatile("s_waitcnt lgkmcnt(0)" ::: "memory");
      if (kt < 3) issueB(kt + 1);
      #pragma unroll
      for (int mf = 0; mf < 2; ++mf)
        #pragma unroll
        for (int nf = 0; nf < 4; ++nf) {
          a2[mf][nf] = __builtin_amdgcn_mfma_f32_16x16x32_bf16(
              a0[mf], b0[nf], a2[mf][nf], 0, 0, 0);
          a2[mf][nf] = __builtin_amdgcn_mfma_f32_16x16x32_bf16(
              a1[mf], b1[nf], a2[mf][nf], 0, 0, 0);
        }
    }
    #pragma unroll
    for (int mf = 0; mf < 2; ++mf)
      #pragma unroll
      for (int nf = 0; nf < 4; ++nf) {
        const int col = ng * 256 + wn + nf * 16 + fr;
        const float bb = ff1_b[col];
        #pragma unroll
        for (int r = 0; r < 4; ++r) {
          const int rl = mf * 16 + fq * 4 + r;
          const float x = fmaxf(a2[mf][nf][r] + bb, 0.f);
          f1_s[rl * 512 + ((col >> 3) ^ (rl & 7)) * 8 + (col & 7)] =
              (ushort_t)f2bf(x);
        }
      }
  }
  __syncthreads();

  // ---------------- phase C: z2 = f1 @ ff2_w + b + y; o = LN2(z2); pool ----
  {
    const ushort_t* Bgl = ff2t + (size_t)(wave * 64 + gl) * 512 + gsw;
    auto issueB = [&](int kt) {
      #pragma unroll
      for (int i = 0; i < 8; ++i)
        gload16(Bgl + (size_t)i * 8 * 512 + kt * 64,
                &Bsm[wave * 4096 + i * 512]);
    };
    fx4 a3[2][4] = {};
    issueB(0);
    #pragma unroll 1
    for (int kt = 0; kt < 8; ++kt) {
      asm volatile("s_waitcnt vmcnt(0)" ::: "memory");
      s16x8 b0[4], b1[4], a0[2], a1[2];
      #pragma unroll
      for (int nf = 0; nf < 4; ++nf) {
        b0[nf] = *(const s16x8*)&Bsm[(wn + nf * 16 + fr) * 64 + x0];
        b1[nf] = *(const s16x8*)&Bsm[(wn + nf * 16 + fr) * 64 + x1];
      }
      #pragma unroll
      for (int mf = 0; mf < 2; ++mf) {
        const int row = mf * 16 + fr;
        a0[mf] = *(const s16x8*)&f1_s[row * 512 + ((kt*8 + fq) ^ (row & 7)) * 8];
        a1[mf] = *(const s16x8*)&f1_s[row * 512 + ((kt*8 + 4 + fq) ^ (row & 7)) * 8];
      }
      asm volatile("s_waitcnt lgkmcnt(0)" ::: "memory");
      if (kt < 7) issueB(kt + 1);
      #pragma unroll
      for (int mf = 0; mf < 2; ++mf)
        #pragma unroll
        for (int nf = 0; nf < 4; ++nf) {
          a3[mf][nf] = __builtin_amdgcn_mfma_f32_16x16x32_bf16(
              a0[mf], b0[nf], a3[mf][nf], 0, 0, 0);
          a3[mf][nf] = __builtin_amdgcn_mfma_f32_16x16x32_bf16(
              a1[mf], b1[nf], a3[mf][nf], 0, 0, 0);
        }
    }
    float vv[2][4][4];
    #pragma unroll
    for (int mf = 0; mf < 2; ++mf)
      #pragma unroll
      for (int nf = 0; nf < 4; ++nf) {
        const int col = wn + nf * 16 + fr;
        const float bb = ff2_b[col];
        #pragma unroll
        for (int r = 0; r < 4; ++r)
          vv[mf][nf][r] = a3[mf][nf][r] + bb + yv[mf][nf][r];
      }
    __syncthreads();
    #pragma unroll
    for (int mf = 0; mf < 2; ++mf)
      #pragma unroll
      for (int r = 0; r < 4; ++r) {
        float s = vv[mf][0][r] + vv[mf][1][r] + vv[mf][2][r] + vv[mf][3][r];
        float q = vv[mf][0][r]*vv[mf][0][r] + vv[mf][1][r]*vv[mf][1][r] +
                  vv[mf][2][r]*vv[mf][2][r] + vv[mf][3][r]*vv[mf][3][r];
        #pragma unroll
        for (int off = 1; off < 16; off <<= 1) {
          s += __shfl_xor(s, off, 64);
          q += __shfl_xor(q, off, 64);
        }
        if (fr == 0) {
          red_s[(mf * 16 + fq * 4 + r) * 4 + wave] = s;
          red_q[(mf * 16 + fq * 4 + r) * 4 + wave] = q;
        }
      }
    __syncthreads();
    float colsum[4] = {};
    #pragma unroll
    for (int mf = 0; mf < 2; ++mf)
      #pragma unroll
      for (int r = 0; r < 4; ++r) {
        const int rl = mf * 16 + fq * 4 + r;
        const float st = red_s[rl*4] + red_s[rl*4+1] + red_s[rl*4+2] + red_s[rl*4+3];
        const float qt = red_q[rl*4] + red_q[rl*4+1] + red_q[rl*4+2] + red_q[rl*4+3];
        const float mu = st * (1.f / 256.f);
        const float rr = rsqrtf(qt * (1.f / 256.f) - mu * mu + 1e-5f);
        #pragma unroll
        for (int nf = 0; nf < 4; ++nf) {
          const int col = wn + nf * 16 + fr;
          colsum[nf] += (vv[mf][nf][r] - mu) * rr * ln2_s[col] + ln2_b[col];
        }
      }
    #pragma unroll
    for (int nf = 0; nf < 4; ++nf) {
      colsum[nf] += __shfl_xor(colsum[nf], 16, 64);
      colsum[nf] += __shfl_xor(colsum[nf], 32, 64);
    }
    if (lane < 16)
      #pragma unroll
      for (int nf = 0; nf < 4; ++nf)
        pooled4[(size_t)bq * 256 + wn + nf * 16 + fr] = colsum[nf];
  }
}

// ---------------------------------------------------------------------------
__global__ __launch_bounds__(256) void head_kernel(
    const float* __restrict__ pooled4, const float* __restrict__ W3,
    const float* __restrict__ b3, const float* __restrict__ W4,
    const float* __restrict__ b4, float* __restrict__ out) {
  __shared__ float sp[256];
  __shared__ float t1[256];
  __shared__ float logits[16];
  const int b = blockIdx.x, h = threadIdx.x;
  sp[h] = pooled4[(size_t)(b * 4 + 0) * 256 + h] +
          pooled4[(size_t)(b * 4 + 1) * 256 + h] +
          pooled4[(size_t)(b * 4 + 2) * 256 + h] +
          pooled4[(size_t)(b * 4 + 3) * 256 + h];
  __syncthreads();
  float a = b3[h];
  for (int k = 0; k < 256; ++k) a += sp[k] * W3[k * 256 + h];
  t1[h] = fmaxf(a, 0.f);
  __syncthreads();
  if (h < 16) {
    float o = b4[h];
    for (int j = 0; j < 256; ++j) o += t1[j] * W4[j * 16 + h];
    logits[h] = o;
  }
  __syncthreads();
  if (h < 16) {
    float mm = -1e30f;
    #pragma unroll
    for (int c = 0; c < 16; ++c) mm = fmaxf(mm, logits[c]);
    float se = 0.f;
    #pragma unroll
    for (int c = 0; c < 16; ++c) se += __expf(logits[c] - mm);
    out[b * 16 + h] = logits[h] - mm - logf(se);
  }
}

// ---------------------------------------------------------------------------
extern "C" void kernel_launch(void* const* d_in, const int* in_sizes, int n_in,
                              void* d_out, int out_size, void* d_ws, size_t ws_size,
                              hipStream_t stream) {
  const float* x_in  = (const float*)d_in[0];
  const float* adj   = (const float*)d_in[1];
  const float* W1    = (const float*)d_in[4];
  const float* b1    = (const float*)d_in[5];
  const float* in_w  = (const float*)d_in[6];
  const float* in_b  = (const float*)d_in[7];
  const float* out_w = (const float*)d_in[8];
  const float* out_b = (const float*)d_in[9];
  const float* ln1_s = (const float*)d_in[10];
  const float* ln1_b = (const float*)d_in[11];
  const float* ff1_w = (const float*)d_in[12];
  const float* ff1_b = (const float*)d_in[13];
  const float* ff2_w = (const float*)d_in[14];
  const float* ff2_b = (const float*)d_in[15];
  const float* ln2_s = (const float*)d_in[16];
  const float* ln2_b = (const float*)d_in[17];
  const float* W3    = (const float*)d_in[18];
  const float* b3    = (const float*)d_in[19];
  const float* W4    = (const float*)d_in[20];
  const float* b4    = (const float*)d_in[21];
  char* ws = (char*)d_ws;
  const size_t MB = 1ull << 20;
  ushort_t* xT      = (ushort_t*)(ws);                 // 4 MB
  ushort_t* W1t     = (ushort_t*)(ws + 4 * MB);
  ushort_t* in_wT   = (ushort_t*)(ws + 4 * MB + 131072);
  ushort_t* out_wT  = (ushort_t*)(ws + 4 * MB + 524288);
  ushort_t* ff1t    = (ushort_t*)(ws + 4 * MB + 655360);
  ushort_t* ff2t    = (ushort_t*)(ws + 4 * MB + 917504);
  float*    p       = (float*)(ws + 8 * MB);           // 8 MB
  ushort_t* p_bf    = (ushort_t*)(ws + 16 * MB);       // 4 MB
  ushort_t* qkv_bf  = (ushort_t*)(ws + 20 * MB);       // 12 MB
  ushort_t* attout  = (ushort_t*)(ws + 32 * MB);       // 4 MB
  float*    pooled4 = (float*)(ws + 36 * MB);          // 256 KB
  ushort_t* part    = (ushort_t*)(ws + 37 * MB);       // 16 MB (4 x bf16)
  float*    outp    = (float*)d_out;
  (void)in_sizes; (void)n_in; (void)out_size; (void)ws_size;

  prep_kernel<<<2304, 256, 0, stream>>>(W1, in_w, out_w, ff1_w, ff2_w,
                                        W1t, in_wT, out_wT, ff1t, ff2t);
  // fc1: xT = (x_in@W1+b1)^T bf16
  gemm2<2, true, 3, false, false><<<dim3(1, 256), 256, 0, stream>>>(
      x_in, W1t, b1, nullptr, nullptr, nullptr, nullptr, xT,
      8192, 256, 256, 256);
  // adjmm7: BM=128 x BN=128 (B traffic halved at 64 acc-VGPRs), KSPLIT=4
  adjmm7<<<dim3(4, 64, 2), 256, 0, stream>>>(adj, xT, part);
  relu_reduce4<<<1024, 256, 0, stream>>>(part, p, p_bf);
  // qkv (bf16 out)
  gemm2<4, false, 1, false, false><<<dim3(3, 128), 256, 0, stream>>>(
      p_bf, in_wT, in_b, nullptr, nullptr, nullptr, nullptr, qkv_bf,
      8192, 768, 256, 256);
  att_fused<<<256, 256, 0, stream>>>(qkv_bf, attout);
  // fused tail: outproj+LN1 -> ff1 -> ff2+LN2 -> pooled partials
  tail_kernel<<<256, 256, 0, stream>>>(
      attout, out_wT, out_b, p, ln1_s, ln1_b, ff1t, ff1_b,
      ff2t, ff2_b, ln2_s, ln2_b, pooled4);
  head_kernel<<<64, 256, 0, stream>>>(pooled4, W3, b3, W4, b4, outp);
}

// Round 16
// 181.781 us; speedup vs baseline: 1.1087x; 1.1087x over previous
//
#include <hip/hip_runtime.h>

typedef float fx4 __attribute__((ext_vector_type(4)));
typedef short s16x8 __attribute__((ext_vector_type(8)));
typedef short s16x4 __attribute__((ext_vector_type(4)));
typedef unsigned short ushort_t;

__device__ __forceinline__ short f2bf(float f) {
  union { float f; unsigned u; } v; v.f = f;
  unsigned r = v.u + 0x7FFFu + ((v.u >> 16) & 1u);   // RNE to bf16
  return (short)(r >> 16);
}

__device__ __forceinline__ float bf2f(short h) {
  union { float f; unsigned u; } v;
  v.u = ((unsigned)(unsigned short)h) << 16;
  return v.f;
}

__device__ __forceinline__ unsigned cvt_pk_bf16(float a, float b) {
  unsigned r;
  asm("v_cvt_pk_bf16_f32 %0, %1, %2" : "=v"(r) : "v"(a), "v"(b));
  return r;
}

__device__ __forceinline__ s16x8 cvt8(fx4 a, fx4 b) {
  union { s16x8 s; unsigned u[4]; } w;
  w.u[0] = cvt_pk_bf16(a[0], a[1]);
  w.u[1] = cvt_pk_bf16(a[2], a[3]);
  w.u[2] = cvt_pk_bf16(b[0], b[1]);
  w.u[3] = cvt_pk_bf16(b[2], b[3]);
  return w.s;
}

__device__ __forceinline__ void gload16(const void* g, void* l) {
  __builtin_amdgcn_global_load_lds(
      (const __attribute__((address_space(1))) unsigned int*)g,
      (__attribute__((address_space(3))) unsigned int*)l, 16, 0, 0);
}

// ---------------------------------------------------------------------------
// prep: all 5 weight transposes W[K][N] fp32 -> Wt[N][K] bf16.
// ---------------------------------------------------------------------------
__global__ __launch_bounds__(256) void prep_kernel(
    const float* __restrict__ W1, const float* __restrict__ in_w,
    const float* __restrict__ out_w, const float* __restrict__ ff1_w,
    const float* __restrict__ ff2_w,
    ushort_t* __restrict__ W1t, ushort_t* __restrict__ in_wT,
    ushort_t* __restrict__ out_wT, ushort_t* __restrict__ ff1t,
    ushort_t* __restrict__ ff2t) {
  const int bid = blockIdx.x, t = threadIdx.x;
  const float* W; ushort_t* Wt; int K, N, base;
  if (bid < 256)       { W = W1;    Wt = W1t;    K = 256; N = 256; base = 0; }
  else if (bid < 1024) { W = in_w;  Wt = in_wT;  K = 256; N = 768; base = 256; }
  else if (bid < 1280) { W = out_w; Wt = out_wT; K = 256; N = 256; base = 1024; }
  else if (bid < 1792) { W = ff1_w; Wt = ff1t;   K = 256; N = 512; base = 1280; }
  else                 { W = ff2_w; Wt = ff2t;   K = 512; N = 256; base = 1792; }
  const int idx = (bid - base) * 256 + t;
  const int k = idx / N, n = idx - k * N;
  Wt[(size_t)n * K + k] = (ushort_t)f2bf(W[idx]);
}

// ---------------------------------------------------------------------------
// Unified 2-phase MFMA GEMM (round-6 structure, verified) — small GEMMs.
// ---------------------------------------------------------------------------
template<int MF, bool AF32, int OUTM, bool RELU, bool RES>
__global__ __launch_bounds__(256) void gemm2(
    const void* __restrict__ Av, const ushort_t* __restrict__ Bt,
    const float* __restrict__ bias, const float* __restrict__ res,
    const float* __restrict__ lns, const float* __restrict__ lnb,
    float* __restrict__ Cf, ushort_t* __restrict__ Cb,
    int M, int N, int K, int kLen) {
  constexpr int BM = MF * 16;
  __shared__ __align__(16) ushort_t Asm[2][BM * 64];
  __shared__ __align__(16) ushort_t Bsm[256 * 64];
  const int t = threadIdx.x, lane = t & 63, wave = t >> 6;
  const int bm = blockIdx.y * BM;
  const int bn = blockIdx.x * 256;
  const int wn = wave * 64, fr = lane & 15, fq = lane >> 4;
  const int NT = kLen >> 6;
  const int x0 = ((fq) ^ (fr & 7)) * 8;
  const int x1 = ((4 + fq) ^ (fr & 7)) * 8;
  fx4 acc[MF][4] = {};

  const int gl = lane >> 3, gc = lane & 7;
  const int gsw = (gc ^ gl) * 8;
  const ushort_t* Bgl = Bt + (size_t)(bn + wave * 64 + gl) * K + gsw;
  const ushort_t* Agl =
      (const ushort_t*)Av + (size_t)(bm + wave * (BM / 4) + gl) * K + gsw;
  constexpr int TPR = 256 / BM;
  const int arow = t / TPR;
  const int ac0 = (t % TPR) * (BM / 4);
  const float* Afp = (const float*)Av + (size_t)(bm + arow) * K + ac0;
  fx4 R[MF / 2][2];

  auto issueB = [&](int kt) {
    #pragma unroll
    for (int i = 0; i < 8; ++i)
      gload16(Bgl + (size_t)i * 8 * K + kt * 64, &Bsm[wave * 4096 + i * 512]);
  };
  auto issueAg = [&](int buf, int kt) {
    #pragma unroll
    for (int i = 0; i < MF / 2; ++i)
      gload16(Agl + (size_t)i * 8 * K + kt * 64,
              &Asm[buf][wave * (BM * 16) + i * 512]);
  };
  auto loadR = [&](int kt) {
    #pragma unroll
    for (int w = 0; w < MF / 2; ++w) {
      R[w][0] = *(const fx4*)(Afp + kt * 64 + w * 8);
      R[w][1] = *(const fx4*)(Afp + kt * 64 + w * 8 + 4);
    }
  };
  auto writeA = [&](int buf) {
    #pragma unroll
    for (int w = 0; w < MF / 2; ++w) {
      const int cs = ((ac0 >> 3) + w) ^ (arow & 7);
      *(s16x8*)&Asm[buf][arow * 64 + cs * 8] = cvt8(R[w][0], R[w][1]);
    }
  };

  if constexpr (AF32) { loadR(0); issueB(0); writeA(0); loadR(1); }
  else { issueAg(0, 0); issueB(0); }
  __syncthreads();

  #pragma unroll 1
  for (int kt = 0; kt < NT; ++kt) {
    const int cur = kt & 1;
    s16x8 b0[4], b1[4], a0[MF], a1[MF];
    #pragma unroll
    for (int nf = 0; nf < 4; ++nf) {
      b0[nf] = *(const s16x8*)&Bsm[(wn + nf * 16 + fr) * 64 + x0];
      b1[nf] = *(const s16x8*)&Bsm[(wn + nf * 16 + fr) * 64 + x1];
    }
    #pragma unroll
    for (int mf = 0; mf < MF; ++mf)
      a0[mf] = *(const s16x8*)&Asm[cur][(mf * 16 + fr) * 64 + x0];
    asm volatile("s_waitcnt lgkmcnt(0)" ::: "memory");
    if (kt + 1 < NT) {
      if constexpr (AF32) {
        writeA(cur ^ 1);
        if (kt + 2 < NT) loadR(kt + 2);
        issueB(kt + 1);
      } else {
        issueAg(cur ^ 1, kt + 1);
        issueB(kt + 1);
      }
    }
    #pragma unroll
    for (int mf = 0; mf < MF; ++mf)
      #pragma unroll
      for (int nf = 0; nf < 4; ++nf)
        acc[mf][nf] = __builtin_amdgcn_mfma_f32_16x16x32_bf16(
            a0[mf], b0[nf], acc[mf][nf], 0, 0, 0);
    #pragma unroll
    for (int mf = 0; mf < MF; ++mf)
      a1[mf] = *(const s16x8*)&Asm[cur][(mf * 16 + fr) * 64 + x1];
    #pragma unroll
    for (int mf = 0; mf < MF; ++mf)
      #pragma unroll
      for (int nf = 0; nf < 4; ++nf)
        acc[mf][nf] = __builtin_amdgcn_mfma_f32_16x16x32_bf16(
            a1[mf], b1[nf], acc[mf][nf], 0, 0, 0);
    __syncthreads();
  }

  if constexpr (OUTM == 3) {
    #pragma unroll
    for (int mf = 0; mf < MF; ++mf)
      #pragma unroll
      for (int nf = 0; nf < 4; ++nf) {
        const int col = bn + wn + nf * 16 + fr;
        const float bb = bias[col];
        s16x4 w;
        #pragma unroll
        for (int r = 0; r < 4; ++r) w[r] = f2bf(acc[mf][nf][r] + bb);
        *(s16x4*)&Cb[(size_t)col * M + bm + mf * 16 + fq * 4] = w;
      }
  } else {
    #pragma unroll
    for (int mf = 0; mf < MF; ++mf)
      #pragma unroll
      for (int nf = 0; nf < 4; ++nf) {
        const int col = bn + wn + nf * 16 + fr;
        const float bb = bias[col];
        #pragma unroll
        for (int r = 0; r < 4; ++r) {
          const int row = bm + mf * 16 + fq * 4 + r;
          float x = acc[mf][nf][r] + bb;
          if constexpr (RES) x += res[(size_t)row * N + col];
          if constexpr (RELU) x = fmaxf(x, 0.f);
          if constexpr (OUTM == 0 || OUTM == 2) Cf[(size_t)row * N + col] = x;
          if constexpr (OUTM == 1 || OUTM == 2)
            Cb[(size_t)row * N + col] = (ushort_t)f2bf(x);
        }
      }
  }
}

// ---------------------------------------------------------------------------
// adjmm2: part[kh] = adj[:, kh*2048:+2048] @ x-chunk, bf16 partials.
// Counted-vmcnt pipeline (r9, verified 183us). Coalesced A lane mapping:
// load j covers a contiguous 64B per row across its 4 lanes, matching 8B
// swizzled writeA. dbuf Asm+Bsm (80 KB, 2 blocks/CU), raw s_barrier,
// vmcnt never drains below 4 mid-loop.
// ---------------------------------------------------------------------------
__global__ __launch_bounds__(256) void adjmm2(
    const float* __restrict__ adj, const ushort_t* __restrict__ xT,
    ushort_t* __restrict__ part) {
  constexpr int NT = 32;                      // 2048 / 64
  __shared__ __align__(16) ushort_t Asm[2][64 * 64];
  __shared__ __align__(16) ushort_t Bsm[2][256 * 64];
  const int t = threadIdx.x, lane = t & 63, wave = t >> 6;
  const int kh = blockIdx.x, bm = blockIdx.y * 64;
  const int kOff = kh * 2048;
  const int wn = wave * 64, fr = lane & 15, fq = lane >> 4;
  const int x0 = (fq ^ (fr & 7)) * 8, x1 = ((4 + fq) ^ (fr & 7)) * 8;
  const int gl = lane >> 3, gc = lane & 7, gsw = (gc ^ gl) * 8;

  const ushort_t* Bgl = xT + (size_t)(wn + gl) * 8192 + kOff + gsw;
  const int arow = t >> 2;                    // 4 threads/row
  const int alane = t & 3;
  const float* Afp = adj + (size_t)(bm + arow) * 8192 + kOff;

  fx4 R[4];                                   // load j: floats [alane*4+16j,+4)
  auto loadR = [&](int kt) {
    #pragma unroll
    for (int j = 0; j < 4; ++j)
      R[j] = *(const fx4*)(Afp + kt * 64 + alane * 4 + j * 16);
  };
  auto writeA = [&](int buf) {
    #pragma unroll
    for (int j = 0; j < 4; ++j) {
      const int cj = alane * 4 + j * 16;       // float offset within row
      const int chunk = cj >> 3;               // 8-float chunk index
      const int sub = cj & 7;                  // 0 or 4
      union { s16x4 s; unsigned u[2]; } w;
      w.u[0] = cvt_pk_bf16(R[j][0], R[j][1]);
      w.u[1] = cvt_pk_bf16(R[j][2], R[j][3]);
      *(s16x4*)&Asm[buf][arow * 64 + (chunk ^ (arow & 7)) * 8 + sub] = w.s;
    }
  };
  auto issueB = [&](int buf, int kt) {
    #pragma unroll
    for (int i = 0; i < 8; ++i)
      gload16(Bgl + (size_t)i * 8 * 8192 + kt * 64,
              &Bsm[buf][wave * 4096 + i * 512]);
  };

  fx4 acc[4][4] = {};
  // prologue: stage tile0 into buf0; tile1 loads in flight into buf1
  loadR(0);
  issueB(0, 0);
  writeA(0);                                  // compiler waits loadR(0) regs
  loadR(1);
  asm volatile("s_waitcnt lgkmcnt(0)" ::: "memory");
  asm volatile("s_waitcnt vmcnt(4)" ::: "memory"); // B(0) landed; loadR(1) flies
  __builtin_amdgcn_sched_barrier(0);
  __builtin_amdgcn_s_barrier();
  __builtin_amdgcn_sched_barrier(0);
  issueB(1, 1);

  #pragma unroll 1
  for (int kt = 0; kt < NT; ++kt) {
    const int cur = kt & 1;
    s16x8 a0[4], a1[4], b0[4], b1[4];
    #pragma unroll
    for (int mf = 0; mf < 4; ++mf) {
      a0[mf] = *(const s16x8*)&Asm[cur][(mf * 16 + fr) * 64 + x0];
      a1[mf] = *(const s16x8*)&Asm[cur][(mf * 16 + fr) * 64 + x1];
    }
    #pragma unroll
    for (int nf = 0; nf < 4; ++nf) {
      b0[nf] = *(const s16x8*)&Bsm[cur][(wn + nf * 16 + fr) * 64 + x0];
      b1[nf] = *(const s16x8*)&Bsm[cur][(wn + nf * 16 + fr) * 64 + x1];
    }
    if (kt + 1 < NT) {
      writeA(cur ^ 1);                        // auto vmcnt for loadR(kt+1)
      if (kt + 2 < NT) loadR(kt + 2);
    }
    #pragma unroll
    for (int mf = 0; mf < 4; ++mf)
      #pragma unroll
      for (int nf = 0; nf < 4; ++nf)
        acc[mf][nf] = __builtin_amdgcn_mfma_f32_16x16x32_bf16(
            a0[mf], b0[nf], acc[mf][nf], 0, 0, 0);
    #pragma unroll
    for (int mf = 0; mf < 4; ++mf)
      #pragma unroll
      for (int nf = 0; nf < 4; ++nf)
        acc[mf][nf] = __builtin_amdgcn_mfma_f32_16x16x32_bf16(
            a1[mf], b1[nf], acc[mf][nf], 0, 0, 0);
    asm volatile("s_waitcnt lgkmcnt(0)" ::: "memory");
    if (kt + 2 < NT)
      asm volatile("s_waitcnt vmcnt(4)" ::: "memory");   // B(kt+1) landed
    else
      asm volatile("s_waitcnt vmcnt(0)" ::: "memory");
    __builtin_amdgcn_sched_barrier(0);
    __builtin_amdgcn_s_barrier();
    __builtin_amdgcn_sched_barrier(0);
    if (kt + 2 < NT) issueB(cur, kt + 2);
  }

  ushort_t* po = part + (size_t)kh * (8192ull * 256ull);
  #pragma unroll
  for (int mf = 0; mf < 4; ++mf)
    #pragma unroll
    for (int nf = 0; nf < 4; ++nf)
      #pragma unroll
      for (int r = 0; r < 4; ++r)
        po[(size_t)(bm + mf * 16 + fq * 4 + r) * 256 + wn + nf * 16 + fr] =
            (ushort_t)f2bf(acc[mf][nf][r]);
}

// sum 4 bf16 partials + relu -> p fp32 + p_bf bf16
__global__ __launch_bounds__(256) void relu_reduce4(
    const ushort_t* __restrict__ part, float* __restrict__ p,
    ushort_t* __restrict__ pb) {
  const size_t i = ((size_t)blockIdx.x * 256 + threadIdx.x) * 8;
  const size_t S = 8192ull * 256ull;
  float a[8] = {};
  #pragma unroll
  for (int j = 0; j < 4; ++j) {
    const s16x8 v = *(const s16x8*)(part + j * S + i);
    #pragma unroll
    for (int c = 0; c < 8; ++c) a[c] += bf2f(v[c]);
  }
  fx4 v0, v1;
  #pragma unroll
  for (int c = 0; c < 4; ++c) {
    v0[c] = fmaxf(a[c], 0.f);
    v1[c] = fmaxf(a[c + 4], 0.f);
  }
  *(fx4*)(p + i) = v0;
  *(fx4*)(p + i + 4) = v1;
  s16x8 w;
  #pragma unroll
  for (int c = 0; c < 4; ++c) { w[c] = f2bf(v0[c]); w[c + 4] = f2bf(v1[c]); }
  *(s16x8*)(pb + i) = w;
}

// ---------------------------------------------------------------------------
// Fused attention, bf16 qkv input. One block per (graph, head).
// ---------------------------------------------------------------------------
__global__ __launch_bounds__(256) void att_fused(
    const ushort_t* __restrict__ qkv, ushort_t* __restrict__ attout) {
  __shared__ float k_s[128][68];
  __shared__ float v_s[128][68];
  __shared__ float s_s[128][129];
  __shared__ float pm[2][128];
  __shared__ float ps[2][128];
  const int bh = blockIdx.x, b = bh >> 2, h = bh & 3;
  const int t = threadIdx.x;
  const ushort_t* qb = qkv + (size_t)b * 128 * 768 + h * 64;
  for (int u = t; u < 1024; u += 256) {
    const int n = u >> 3, d8 = (u & 7) * 8;
    const s16x8 kk = *(const s16x8*)(qb + (size_t)n * 768 + 256 + d8);
    const s16x8 vv = *(const s16x8*)(qb + (size_t)n * 768 + 512 + d8);
    #pragma unroll
    for (int c = 0; c < 8; ++c) {
      k_s[n][d8 + c] = bf2f(kk[c]);
      v_s[n][d8 + c] = bf2f(vv[c]);
    }
  }
  const int row = t & 127, kh = t >> 7;
  fx4 qr[16];
  {
    const s16x8* q8 = (const s16x8*)(qb + (size_t)row * 768);
    #pragma unroll
    for (int j = 0; j < 8; ++j) {
      const s16x8 qv = q8[j];
      qr[2*j][0] = bf2f(qv[0]); qr[2*j][1] = bf2f(qv[1]);
      qr[2*j][2] = bf2f(qv[2]); qr[2*j][3] = bf2f(qv[3]);
      qr[2*j+1][0] = bf2f(qv[4]); qr[2*j+1][1] = bf2f(qv[5]);
      qr[2*j+1][2] = bf2f(qv[6]); qr[2*j+1][3] = bf2f(qv[7]);
    }
  }
  __syncthreads();
  float m = -1e30f;
  for (int j = 0; j < 64; ++j) {
    const int jj = kh * 64 + j;
    const fx4* kr = (const fx4*)&k_s[jj][0];
    float s0 = 0.f, s1 = 0.f, s2 = 0.f, s3 = 0.f;
    #pragma unroll
    for (int c = 0; c < 16; c += 4) {
      fx4 k0 = kr[c], k1 = kr[c + 1], k2 = kr[c + 2], k3 = kr[c + 3];
      s0 += qr[c][0]*k0[0] + qr[c][1]*k0[1] + qr[c][2]*k0[2] + qr[c][3]*k0[3];
      s1 += qr[c+1][0]*k1[0] + qr[c+1][1]*k1[1] + qr[c+1][2]*k1[2] + qr[c+1][3]*k1[3];
      s2 += qr[c+2][0]*k2[0] + qr[c+2][1]*k2[1] + qr[c+2][2]*k2[2] + qr[c+2][3]*k2[3];
      s3 += qr[c+3][0]*k3[0] + qr[c+3][1]*k3[1] + qr[c+3][2]*k3[2] + qr[c+3][3]*k3[3];
    }
    const float s = (s0 + s1 + s2 + s3) * 0.125f;
    s_s[row][jj] = s;
    m = fmaxf(m, s);
  }
  pm[kh][row] = m;
  __syncthreads();
  const float m2 = fmaxf(pm[0][row], pm[1][row]);
  float sum = 0.f;
  for (int j = 0; j < 64; ++j) {
    const int jj = kh * 64 + j;
    const float e = __expf(s_s[row][jj] - m2);
    s_s[row][jj] = e;
    sum += e;
  }
  ps[kh][row] = sum;
  __syncthreads();
  const int row2 = t >> 1, dh = (t & 1) * 32;
  const float inv = 1.f / (ps[0][row2] + ps[1][row2]);
  fx4 acc4[8] = {};
  for (int k = 0; k < 128; ++k) {
    const float e = s_s[row2][k];
    const fx4* vr = (const fx4*)&v_s[k][dh];
    #pragma unroll
    for (int c = 0; c < 8; ++c) acc4[c] += e * vr[c];
  }
  ushort_t* orow = attout + (size_t)(b * 128 + row2) * 256 + h * 64 + dh;
  #pragma unroll
  for (int c = 0; c < 8; ++c) {
    const fx4 v = acc4[c] * inv;
    s16x4 w;
    #pragma unroll
    for (int j = 0; j < 4; ++j) w[j] = f2bf(v[j]);
    *(s16x4*)(orow + c * 4) = w;
  }
}

// ---------------------------------------------------------------------------
// Fused tail: outproj+res+LN1 -> ff1+relu -> ff2+res+LN2 -> 32-row col-sums.
// ---------------------------------------------------------------------------
__global__ __launch_bounds__(256) void tail_kernel(
    const ushort_t* __restrict__ attout, const ushort_t* __restrict__ out_wT,
    const float* __restrict__ out_b, const float* __restrict__ p_res,
    const float* __restrict__ ln1_s, const float* __restrict__ ln1_b,
    const ushort_t* __restrict__ ff1t, const float* __restrict__ ff1_b,
    const ushort_t* __restrict__ ff2t, const float* __restrict__ ff2_b,
    const float* __restrict__ ln2_s, const float* __restrict__ ln2_b,
    float* __restrict__ pooled4) {
  __shared__ __align__(16) ushort_t Asm[2][32 * 64];
  __shared__ __align__(16) ushort_t Bsm[256 * 64];
  __shared__ __align__(16) ushort_t y_s[32 * 256];
  __shared__ __align__(16) ushort_t f1_s[32 * 512];
  __shared__ float red_s[128], red_q[128];
  const int t = threadIdx.x, lane = t & 63, wave = t >> 6;
  const int bq = blockIdx.x, bm = bq * 32;
  const int wn = wave * 64, fr = lane & 15, fq = lane >> 4;
  const int x0 = (fq ^ (fr & 7)) * 8, x1 = ((4 + fq) ^ (fr & 7)) * 8;
  const int gl = lane >> 3, gc = lane & 7, gsw = (gc ^ gl) * 8;

  fx4 acc[2][4] = {};
  // ---------------- phase A: z = attout@out_w + b + p; y = LN1(z) ----------
  {
    const ushort_t* Agl = attout + (size_t)(bm + wave * 8 + gl) * 256 + gsw;
    const ushort_t* Bgl = out_wT + (size_t)(wave * 64 + gl) * 256 + gsw;
    auto issueA = [&](int buf, int kt) {
      gload16(Agl + kt * 64, &Asm[buf][wave * 512]);
    };
    auto issueB = [&](int kt) {
      #pragma unroll
      for (int i = 0; i < 8; ++i)
        gload16(Bgl + (size_t)i * 8 * 256 + kt * 64,
                &Bsm[wave * 4096 + i * 512]);
    };
    issueA(0, 0); issueB(0);
    __syncthreads();
    #pragma unroll 1
    for (int kt = 0; kt < 4; ++kt) {
      const int cur = kt & 1;
      s16x8 b0[4], b1[4], a0[2], a1[2];
      #pragma unroll
      for (int nf = 0; nf < 4; ++nf) {
        b0[nf] = *(const s16x8*)&Bsm[(wn + nf * 16 + fr) * 64 + x0];
        b1[nf] = *(const s16x8*)&Bsm[(wn + nf * 16 + fr) * 64 + x1];
      }
      #pragma unroll
      for (int mf = 0; mf < 2; ++mf) {
        a0[mf] = *(const s16x8*)&Asm[cur][(mf * 16 + fr) * 64 + x0];
        a1[mf] = *(const s16x8*)&Asm[cur][(mf * 16 + fr) * 64 + x1];
      }
      asm volatile("s_waitcnt lgkmcnt(0)" ::: "memory");
      if (kt < 3) { issueA(cur ^ 1, kt + 1); issueB(kt + 1); }
      #pragma unroll
      for (int mf = 0; mf < 2; ++mf)
        #pragma unroll
        for (int nf = 0; nf < 4; ++nf) {
          acc[mf][nf] = __builtin_amdgcn_mfma_f32_16x16x32_bf16(
              a0[mf], b0[nf], acc[mf][nf], 0, 0, 0);
          acc[mf][nf] = __builtin_amdgcn_mfma_f32_16x16x32_bf16(
              a1[mf], b1[nf], acc[mf][nf], 0, 0, 0);
        }
      __syncthreads();
    }
  }
  float yv[2][4][4];
  #pragma unroll
  for (int mf = 0; mf < 2; ++mf)
    #pragma unroll
    for (int nf = 0; nf < 4; ++nf) {
      const int col = wn + nf * 16 + fr;
      #pragma unroll
      for (int r = 0; r < 4; ++r) {
        const int row = bm + mf * 16 + fq * 4 + r;
        yv[mf][nf][r] = acc[mf][nf][r] + out_b[col] +
                        p_res[(size_t)row * 256 + col];
      }
    }
  {
    #pragma unroll
    for (int mf = 0; mf < 2; ++mf)
      #pragma unroll
      for (int r = 0; r < 4; ++r) {
        float s = yv[mf][0][r] + yv[mf][1][r] + yv[mf][2][r] + yv[mf][3][r];
        float q = yv[mf][0][r]*yv[mf][0][r] + yv[mf][1][r]*yv[mf][1][r] +
                  yv[mf][2][r]*yv[mf][2][r] + yv[mf][3][r]*yv[mf][3][r];
        #pragma unroll
        for (int off = 1; off < 16; off <<= 1) {
          s += __shfl_xor(s, off, 64);
          q += __shfl_xor(q, off, 64);
        }
        if (fr == 0) {
          red_s[(mf * 16 + fq * 4 + r) * 4 + wave] = s;
          red_q[(mf * 16 + fq * 4 + r) * 4 + wave] = q;
        }
      }
    __syncthreads();
    #pragma unroll
    for (int mf = 0; mf < 2; ++mf)
      #pragma unroll
      for (int r = 0; r < 4; ++r) {
        const int rl = mf * 16 + fq * 4 + r;
        const float st = red_s[rl*4] + red_s[rl*4+1] + red_s[rl*4+2] + red_s[rl*4+3];
        const float qt = red_q[rl*4] + red_q[rl*4+1] + red_q[rl*4+2] + red_q[rl*4+3];
        const float mu = st * (1.f / 256.f);
        const float rr = rsqrtf(qt * (1.f / 256.f) - mu * mu + 1e-5f);
        #pragma unroll
        for (int nf = 0; nf < 4; ++nf) {
          const int col = wn + nf * 16 + fr;
          const float o = (yv[mf][nf][r] - mu) * rr * ln1_s[col] + ln1_b[col];
          yv[mf][nf][r] = o;
          y_s[rl * 256 + ((col >> 3) ^ (rl & 7)) * 8 + (col & 7)] =
              (ushort_t)f2bf(o);
        }
      }
  }
  __syncthreads();

  // ---------------- phase B: f1 = relu(y @ ff1_w + b) ----------------------
  #pragma unroll 1
  for (int ng = 0; ng < 2; ++ng) {
    const ushort_t* Bgl = ff1t + (size_t)(ng * 256 + wave * 64 + gl) * 256 + gsw;
    auto issueB = [&](int kt) {
      #pragma unroll
      for (int i = 0; i < 8; ++i)
        gload16(Bgl + (size_t)i * 8 * 256 + kt * 64,
                &Bsm[wave * 4096 + i * 512]);
    };
    fx4 a2[2][4] = {};
    issueB(0);
    #pragma unroll 1
    for (int kt = 0; kt < 4; ++kt) {
      asm volatile("s_waitcnt vmcnt(0)" ::: "memory");
      s16x8 b0[4], b1[4], a0[2], a1[2];
      #pragma unroll
      for (int nf = 0; nf < 4; ++nf) {
        b0[nf] = *(const s16x8*)&Bsm[(wn + nf * 16 + fr) * 64 + x0];
        b1[nf] = *(const s16x8*)&Bsm[(wn + nf * 16 + fr) * 64 + x1];
      }
      #pragma unroll
      for (int mf = 0; mf < 2; ++mf) {
        const int row = mf * 16 + fr;
        a0[mf] = *(const s16x8*)&y_s[row * 256 + ((kt*8 + fq) ^ (row & 7)) * 8];
        a1[mf] = *(const s16x8*)&y_s[row * 256 + ((kt*8 + 4 + fq) ^ (row & 7)) * 8];
      }
      asm volatile("s_waitcnt lgkmcnt(0)" ::: "memory");
      if (kt < 3) issueB(kt + 1);
      #pragma unroll
      for (int mf = 0; mf < 2; ++mf)
        #pragma unroll
        for (int nf = 0; nf < 4; ++nf) {
          a2[mf][nf] = __builtin_amdgcn_mfma_f32_16x16x32_bf16(
              a0[mf], b0[nf], a2[mf][nf], 0, 0, 0);
          a2[mf][nf] = __builtin_amdgcn_mfma_f32_16x16x32_bf16(
              a1[mf], b1[nf], a2[mf][nf], 0, 0, 0);
        }
    }
    #pragma unroll
    for (int mf = 0; mf < 2; ++mf)
      #pragma unroll
      for (int nf = 0; nf < 4; ++nf) {
        const int col = ng * 256 + wn + nf * 16 + fr;
        const float bb = ff1_b[col];
        #pragma unroll
        for (int r = 0; r < 4; ++r) {
          const int rl = mf * 16 + fq * 4 + r;
          const float x = fmaxf(a2[mf][nf][r] + bb, 0.f);
          f1_s[rl * 512 + ((col >> 3) ^ (rl & 7)) * 8 + (col & 7)] =
              (ushort_t)f2bf(x);
        }
      }
  }
  __syncthreads();

  // ---------------- phase C: z2 = f1 @ ff2_w + b + y; o = LN2(z2); pool ----
  {
    const ushort_t* Bgl = ff2t + (size_t)(wave * 64 + gl) * 512 + gsw;
    auto issueB = [&](int kt) {
      #pragma unroll
      for (int i = 0; i < 8; ++i)
        gload16(Bgl + (size_t)i * 8 * 512 + kt * 64,
                &Bsm[wave * 4096 + i * 512]);
    };
    fx4 a3[2][4] = {};
    issueB(0);
    #pragma unroll 1
    for (int kt = 0; kt < 8; ++kt) {
      asm volatile("s_waitcnt vmcnt(0)" ::: "memory");
      s16x8 b0[4], b1[4], a0[2], a1[2];
      #pragma unroll
      for (int nf = 0; nf < 4; ++nf) {
        b0[nf] = *(const s16x8*)&Bsm[(wn + nf * 16 + fr) * 64 + x0];
        b1[nf] = *(const s16x8*)&Bsm[(wn + nf * 16 + fr) * 64 + x1];
      }
      #pragma unroll
      for (int mf = 0; mf < 2; ++mf) {
        const int row = mf * 16 + fr;
        a0[mf] = *(const s16x8*)&f1_s[row * 512 + ((kt*8 + fq) ^ (row & 7)) * 8];
        a1[mf] = *(const s16x8*)&f1_s[row * 512 + ((kt*8 + 4 + fq) ^ (row & 7)) * 8];
      }
      asm volatile("s_waitcnt lgkmcnt(0)" ::: "memory");
      if (kt < 7) issueB(kt + 1);
      #pragma unroll
      for (int mf = 0; mf < 2; ++mf)
        #pragma unroll
        for (int nf = 0; nf < 4; ++nf) {
          a3[mf][nf] = __builtin_amdgcn_mfma_f32_16x16x32_bf16(
              a0[mf], b0[nf], a3[mf][nf], 0, 0, 0);
          a3[mf][nf] = __builtin_amdgcn_mfma_f32_16x16x32_bf16(
              a1[mf], b1[nf], a3[mf][nf], 0, 0, 0);
        }
    }
    float vv[2][4][4];
    #pragma unroll
    for (int mf = 0; mf < 2; ++mf)
      #pragma unroll
      for (int nf = 0; nf < 4; ++nf) {
        const int col = wn + nf * 16 + fr;
        const float bb = ff2_b[col];
        #pragma unroll
        for (int r = 0; r < 4; ++r)
          vv[mf][nf][r] = a3[mf][nf][r] + bb + yv[mf][nf][r];
      }
    __syncthreads();
    #pragma unroll
    for (int mf = 0; mf < 2; ++mf)
      #pragma unroll
      for (int r = 0; r < 4; ++r) {
        float s = vv[mf][0][r] + vv[mf][1][r] + vv[mf][2][r] + vv[mf][3][r];
        float q = vv[mf][0][r]*vv[mf][0][r] + vv[mf][1][r]*vv[mf][1][r] +
                  vv[mf][2][r]*vv[mf][2][r] + vv[mf][3][r]*vv[mf][3][r];
        #pragma unroll
        for (int off = 1; off < 16; off <<= 1) {
          s += __shfl_xor(s, off, 64);
          q += __shfl_xor(q, off, 64);
        }
        if (fr == 0) {
          red_s[(mf * 16 + fq * 4 + r) * 4 + wave] = s;
          red_q[(mf * 16 + fq * 4 + r) * 4 + wave] = q;
        }
      }
    __syncthreads();
    float colsum[4] = {};
    #pragma unroll
    for (int mf = 0; mf < 2; ++mf)
      #pragma unroll
      for (int r = 0; r < 4; ++r) {
        const int rl = mf * 16 + fq * 4 + r;
        const float st = red_s[rl*4] + red_s[rl*4+1] + red_s[rl*4+2] + red_s[rl*4+3];
        const float qt = red_q[rl*4] + red_q[rl*4+1] + red_q[rl*4+2] + red_q[rl*4+3];
        const float mu = st * (1.f / 256.f);
        const float rr = rsqrtf(qt * (1.f / 256.f) - mu * mu + 1e-5f);
        #pragma unroll
        for (int nf = 0; nf < 4; ++nf) {
          const int col = wn + nf * 16 + fr;
          colsum[nf] += (vv[mf][nf][r] - mu) * rr * ln2_s[col] + ln2_b[col];
        }
      }
    #pragma unroll
    for (int nf = 0; nf < 4; ++nf) {
      colsum[nf] += __shfl_xor(colsum[nf], 16, 64);
      colsum[nf] += __shfl_xor(colsum[nf], 32, 64);
    }
    if (lane < 16)
      #pragma unroll
      for (int nf = 0; nf < 4; ++nf)
        pooled4[(size_t)bq * 256 + wn + nf * 16 + fr] = colsum[nf];
  }
}

// ---------------------------------------------------------------------------
__global__ __launch_bounds__(256) void head_kernel(
    const float* __restrict__ pooled4, const float* __restrict__ W3,
    const float* __restrict__ b3, const float* __restrict__ W4,
    const float* __restrict__ b4, float* __restrict__ out) {
  __shared__ float sp[256];
  __shared__ float t1[256];
  __shared__ float logits[16];
  const int b = blockIdx.x, h = threadIdx.x;
  sp[h] = pooled4[(size_t)(b * 4 + 0) * 256 + h] +
          pooled4[(size_t)(b * 4 + 1) * 256 + h] +
          pooled4[(size_t)(b * 4 + 2) * 256 + h] +
          pooled4[(size_t)(b * 4 + 3) * 256 + h];
  __syncthreads();
  float a = b3[h];
  for (int k = 0; k < 256; ++k) a += sp[k] * W3[k * 256 + h];
  t1[h] = fmaxf(a, 0.f);
  __syncthreads();
  if (h < 16) {
    float o = b4[h];
    for (int j = 0; j < 256; ++j) o += t1[j] * W4[j * 16 + h];
    logits[h] = o;
  }
  __syncthreads();
  if (h < 16) {
    float mm = -1e30f;
    #pragma unroll
    for (int c = 0; c < 16; ++c) mm = fmaxf(mm, logits[c]);
    float se = 0.f;
    #pragma unroll
    for (int c = 0; c < 16; ++c) se += __expf(logits[c] - mm);
    out[b * 16 + h] = logits[h] - mm - logf(se);
  }
}

// ---------------------------------------------------------------------------
extern "C" void kernel_launch(void* const* d_in, const int* in_sizes, int n_in,
                              void* d_out, int out_size, void* d_ws, size_t ws_size,
                              hipStream_t stream) {
  const float* x_in  = (const float*)d_in[0];
  const float* adj   = (const float*)d_in[1];
  const float* W1    = (const float*)d_in[4];
  const float* b1    = (const float*)d_in[5];
  const float* in_w  = (const float*)d_in[6];
  const float* in_b  = (const float*)d_in[7];
  const float* out_w = (const float*)d_in[8];
  const float* out_b = (const float*)d_in[9];
  const float* ln1_s = (const float*)d_in[10];
  const float* ln1_b = (const float*)d_in[11];
  const float* ff1_w = (const float*)d_in[12];
  const float* ff1_b = (const float*)d_in[13];
  const float* ff2_w = (const float*)d_in[14];
  const float* ff2_b = (const float*)d_in[15];
  const float* ln2_s = (const float*)d_in[16];
  const float* ln2_b = (const float*)d_in[17];
  const float* W3    = (const float*)d_in[18];
  const float* b3    = (const float*)d_in[19];
  const float* W4    = (const float*)d_in[20];
  const float* b4    = (const float*)d_in[21];
  char* ws = (char*)d_ws;
  const size_t MB = 1ull << 20;
  ushort_t* xT      = (ushort_t*)(ws);                 // 4 MB
  ushort_t* W1t     = (ushort_t*)(ws + 4 * MB);
  ushort_t* in_wT   = (ushort_t*)(ws + 4 * MB + 131072);
  ushort_t* out_wT  = (ushort_t*)(ws + 4 * MB + 524288);
  ushort_t* ff1t    = (ushort_t*)(ws + 4 * MB + 655360);
  ushort_t* ff2t    = (ushort_t*)(ws + 4 * MB + 917504);
  float*    p       = (float*)(ws + 8 * MB);           // 8 MB
  ushort_t* p_bf    = (ushort_t*)(ws + 16 * MB);       // 4 MB
  ushort_t* qkv_bf  = (ushort_t*)(ws + 20 * MB);       // 12 MB
  ushort_t* attout  = (ushort_t*)(ws + 32 * MB);       // 4 MB
  float*    pooled4 = (float*)(ws + 36 * MB);          // 256 KB
  ushort_t* part    = (ushort_t*)(ws + 37 * MB);       // 16 MB (4 x bf16)
  float*    outp    = (float*)d_out;
  (void)in_sizes; (void)n_in; (void)out_size; (void)ws_size;

  prep_kernel<<<2304, 256, 0, stream>>>(W1, in_w, out_w, ff1_w, ff2_w,
                                        W1t, in_wT, out_wT, ff1t, ff2t);
  // fc1: xT = (x_in@W1+b1)^T bf16
  gemm2<2, true, 3, false, false><<<dim3(1, 256), 256, 0, stream>>>(
      x_in, W1t, b1, nullptr, nullptr, nullptr, nullptr, xT,
      8192, 256, 256, 256);
  // adjmm2: 4-way K-split bf16 partials, counted-vmcnt pipeline, coalesced A
  adjmm2<<<dim3(4, 128), 256, 0, stream>>>(adj, xT, part);
  relu_reduce4<<<1024, 256, 0, stream>>>(part, p, p_bf);
  // qkv (bf16 out)
  gemm2<4, false, 1, false, false><<<dim3(3, 128), 256, 0, stream>>>(
      p_bf, in_wT, in_b, nullptr, nullptr, nullptr, nullptr, qkv_bf,
      8192, 768, 256, 256);
  att_fused<<<256, 256, 0, stream>>>(qkv_bf, attout);
  // fused tail: outproj+LN1 -> ff1 -> ff2+LN2 -> pooled partials
  tail_kernel<<<256, 256, 0, stream>>>(
      attout, out_wT, out_b, p, ln1_s, ln1_b, ff1t, ff1_b,
      ff2t, ff2_b, ln2_s, ln2_b, pooled4);
  head_kernel<<<64, 256, 0, stream>>>(pooled4, W3, b3, W4, b4, outp);
}